// Round 8
// baseline (282.814 us; speedup 1.0000x reference)
//
#include <hip/hip_runtime.h>
#include <hip/hip_bf16.h>
#include <math.h>

#define Cch 64
#define Hh  256
#define Ww  256
#define HW  (Hh * 256)

// ws layout (32-bit words):
// [0, 10240):  A-frags [4 g][5 s][64 lane][8 u32]  (hi 4, lo 4)
#define WS_WC2  10240    // [16][16] f32 conv2 center taps
#define WS_SC   10496    // [16] BN scale
#define WS_OFF  10512    // [16] BN offset (incl conv2 bias)

typedef __attribute__((ext_vector_type(8))) short bf16x8;
typedef __attribute__((ext_vector_type(4))) float f32x4;

__device__ __forceinline__ float mishf(float x) {
    float e  = __expf(fminf(x, 15.0f));
    float n  = 1.0f + e;
    float n2 = n * n;
    float t  = __fdividef(n2 - 1.0f, n2 + 1.0f);
    return x > 15.0f ? x : x * t;
}

__device__ __forceinline__ unsigned packbf(float a, float b) {
    unsigned short ua = __builtin_bit_cast(unsigned short, __float2bfloat16(a));
    unsigned short ub = __builtin_bit_cast(unsigned short, __float2bfloat16(b));
    return (unsigned)ua | ((unsigned)ub << 16);
}

// conv1 weight for (group g, output m, chunk s, quarter qt, j):
// s<4: channel c=g*16+4s+qt, j<3: m_kh(kw=j), j in 3..5: m_kw(kh=j-3), j>=6: 0
// s==4 (gmax chunk): k=8*qt+j, k<9 -> m_gc weight, else 0
__device__ __forceinline__ float conv1_wval(const float* w1, int g, int m,
                                            int s, int qt, int j) {
    if (s < 4) {
        if (j >= 6) return 0.0f;
        int c = g * 16 + 4 * s + qt;
        return (j < 3) ? w1[m * 420 + 36 + c * 3 + j]
                       : w1[m * 420 + 228 + c * 3 + (j - 3)];
    }
    int k = 8 * qt + j;
    return (k < 9) ? w1[m * 420 + g * 9 + k] : 0.0f;
}

__global__ __launch_bounds__(256) void prep_kernel(
    const float* __restrict__ w1, const float* __restrict__ w2,
    const float* __restrict__ b2,
    const float* __restrict__ gamma, const float* __restrict__ beta,
    const float* __restrict__ mean,  const float* __restrict__ var,
    float* __restrict__ ws)
{
    unsigned* wsu = (unsigned*)ws;
    const int tid = threadIdx.x;

    for (int idx = tid; idx < 1280; idx += 256) {
        int g = idx / 320, s = (idx / 64) % 5, lane = idx % 64;
        int m = lane & 15, qt = lane >> 4;
        unsigned hi[4], lo[4];
        #pragma unroll
        for (int jp = 0; jp < 4; ++jp) {
            float hv[2], lv[2];
            #pragma unroll
            for (int e = 0; e < 2; ++e) {
                float v  = conv1_wval(w1, g, m, s, qt, jp * 2 + e);
                float hf = __bfloat162float(__float2bfloat16(v));
                hv[e] = hf;
                lv[e] = v - hf;
            }
            hi[jp] = packbf(hv[0], hv[1]);
            lo[jp] = packbf(lv[0], lv[1]);
        }
        int b0 = idx * 8;
        #pragma unroll
        for (int i = 0; i < 4; ++i) { wsu[b0 + i] = hi[i]; wsu[b0 + 4 + i] = lo[i]; }
    }

    for (int idx = tid; idx < 256; idx += 256) {
        int o = idx / 16, i = idx % 16;
        ws[WS_WC2 + idx] = w2[o * 144 + i * 9 + 4];
    }
    if (tid < 16) {
        float sc = gamma[tid] * rsqrtf(var[tid] + 1e-5f);
        ws[WS_SC + tid]  = sc;
        ws[WS_OFF + tid] = b2[tid] * sc + beta[tid] - mean[tid] * sc;
    }
}

// ---- fences: order LDS slab write->read / read->overwrite at compile+HW ----
#define LDS_FENCE() do {                                             \
    asm volatile("s_waitcnt lgkmcnt(0)" ::: "memory");               \
    __builtin_amdgcn_sched_barrier(0);                               \
} while (0)
#define ORDER_FENCE() do {                                           \
    asm volatile("" ::: "memory");                                   \
    __builtin_amdgcn_sched_barrier(0);                               \
} while (0)

#define LOAD9(dst, cb) do {                                          \
    const float* r0_ = (cb) + (size_t)hmc * Ww + w;                  \
    const float* r1_ = (cb) + (size_t)h   * Ww + w;                  \
    const float* r2_ = (cb) + (size_t)hpc * Ww + w;                  \
    (dst)[0] = r0_[offm]; (dst)[1] = r0_[0]; (dst)[2] = r0_[offp];   \
    (dst)[3] = r1_[offm]; (dst)[4] = r1_[0]; (dst)[5] = r1_[offp];   \
    (dst)[6] = r2_[offm]; (dst)[7] = r2_[0]; (dst)[8] = r2_[offp];   \
} while (0)

// 36-load batch for channel-chunk S (channels 4S..4S+3 of this group)
#define CHUNK_LOAD(P, S) do {                                        \
    _Pragma("unroll")                                                \
    for (int i_ = 0; i_ < 4; ++i_)                                   \
        LOAD9(&(P)[9 * i_], base + (size_t)(4 * (S) + i_) * HW);     \
} while (0)

// mask in place + gmax + pack + slab write + MFMA for chunk S
#define PHA_PROC(P, S, INIT) do {                                    \
    const uint4* wa_ = (const uint4*)ws;                             \
    uint4 Ahi_ = wa_[((g * 5 + (S)) * 64 + l) * 2];                  \
    uint4 Alo_ = wa_[((g * 5 + (S)) * 64 + l) * 2 + 1];              \
    _Pragma("unroll")                                                \
    for (int i_ = 0; i_ < 4; ++i_) {                                 \
        float* q_ = &(P)[9 * i_];                                    \
        q_[0] = (okhm && okm) ? q_[0] : 0.0f;                        \
        q_[1] =  okhm         ? q_[1] : 0.0f;                        \
        q_[2] = (okhm && okp) ? q_[2] : 0.0f;                        \
        q_[3] =  okm          ? q_[3] : 0.0f;                        \
        q_[5] =  okp          ? q_[5] : 0.0f;                        \
        q_[6] = (okhp && okm) ? q_[6] : 0.0f;                        \
        q_[7] =  okhp         ? q_[7] : 0.0f;                        \
        q_[8] = (okhp && okp) ? q_[8] : 0.0f;                        \
        if ((INIT) && i_ == 0) {                                     \
            _Pragma("unroll")                                        \
            for (int k_ = 0; k_ < 9; ++k_) gmax[k_] = q_[k_];        \
        } else {                                                     \
            _Pragma("unroll")                                        \
            for (int k_ = 0; k_ < 9; ++k_)                           \
                gmax[k_] = fmaxf(gmax[k_], q_[k_]);                  \
        }                                                            \
        float mkh0 = fmaxf(fmaxf(q_[0], q_[3]), q_[6]);              \
        float mkh1 = fmaxf(fmaxf(q_[1], q_[4]), q_[7]);              \
        float mkh2 = fmaxf(fmaxf(q_[2], q_[5]), q_[8]);              \
        float mkw0 = fmaxf(fmaxf(q_[0], q_[1]), q_[2]);              \
        float mkw1 = fmaxf(fmaxf(q_[3], q_[4]), q_[5]);              \
        float mkw2 = fmaxf(fmaxf(q_[6], q_[7]), q_[8]);              \
        uint4 v_;                                                    \
        v_.x = packbf(mkh0, mkh1);                                   \
        v_.y = packbf(mkh2, mkw0);                                   \
        v_.z = packbf(mkw1, mkw2);                                   \
        v_.w = 0u;                                                   \
        slab[g][l * 5 + i_] = v_;                                    \
    }                                                                \
    LDS_FENCE();                                                     \
    _Pragma("unroll")                                                \
    for (int t_ = 0; t_ < 4; ++t_) {                                 \
        uint4 bv_ = slab[g][(16 * t_ + ln) * 5 + half];              \
        acc[t_] = __builtin_amdgcn_mfma_f32_16x16x32_bf16(           \
            __builtin_bit_cast(bf16x8, Ahi_),                        \
            __builtin_bit_cast(bf16x8, bv_), acc[t_], 0, 0, 0);      \
        acc[t_] = __builtin_amdgcn_mfma_f32_16x16x32_bf16(           \
            __builtin_bit_cast(bf16x8, Alo_),                        \
            __builtin_bit_cast(bf16x8, bv_), acc[t_], 0, 0, 0);      \
    }                                                                \
    ORDER_FENCE();                                                   \
} while (0)

// masked att-weighted reduction + store for chunk S
#define AGG_PROC(P, S) do {                                          \
    _Pragma("unroll")                                                \
    for (int i_ = 0; i_ < 4; ++i_) {                                 \
        const float* q_ = &(P)[9 * i_];                              \
        float a2_ = 0.0f;                                            \
        a2_ = fmaf((okhm && okm) ? q_[0] : 0.0f, att[0], a2_);       \
        a2_ = fmaf( okhm         ? q_[1] : 0.0f, att[1], a2_);       \
        a2_ = fmaf((okhm && okp) ? q_[2] : 0.0f, att[2], a2_);       \
        a2_ = fmaf( okm          ? q_[3] : 0.0f, att[3], a2_);       \
        a2_ = fmaf( q_[4],                       att[4], a2_);       \
        a2_ = fmaf( okp          ? q_[5] : 0.0f, att[5], a2_);       \
        a2_ = fmaf((okhp && okm) ? q_[6] : 0.0f, att[6], a2_);       \
        a2_ = fmaf( okhp         ? q_[7] : 0.0f, att[7], a2_);       \
        a2_ = fmaf((okhp && okp) ? q_[8] : 0.0f, att[8], a2_);       \
        ob[(size_t)(4 * (S) + i_) * HW] = a2_;                       \
    }                                                                \
} while (0)

__global__ __launch_bounds__(256, 4) void revo_kernel(
    const float* __restrict__ in,
    const float* __restrict__ b1,
    const float* __restrict__ w3, const float* __restrict__ b3,
    const float* __restrict__ ws,
    float* __restrict__ out)
{
    const int tid  = threadIdx.x;
    const int g    = __builtin_amdgcn_readfirstlane(tid >> 6);
    const int l    = tid & 63;

    const int bid     = blockIdx.x;
    const int logical = ((bid & 7) << 8) + (bid >> 3);  // XCD-chunked
    const int wseg = logical & 3;
    const int h    = (logical >> 2) & (Hh - 1);
    const int b    = logical >> 10;
    const int w    = wseg * 64 + l;

    // Per-wave recycled B-slab (stride-5 uint4 lines) + stride-17 y-exchange.
    // 20 KB + 17.4 KB = 37.9 KB -> 4 blocks/CU.
    __shared__ uint4 slab[4][320];
    __shared__ float ldsy[4][64][17];

    const float* base = in + ((size_t)b * Cch + g * 16) * HW;

    const bool okm = (w > 0);
    const bool okp = (w < Ww - 1);
    const int offm = okm ? -1 : 0;
    const int offp = okp ?  1 : 0;

    const int hm = h - 1, hp = h + 1;
    const bool okhm = (hm >= 0), okhp = (hp < Hh);
    const int hmc = okhm ? hm : 0;
    const int hpc = okhp ? hp : Hh - 1;

    const int ln = l & 15, half = l >> 4;

    f32x4 acc[4];
    #pragma unroll
    for (int t = 0; t < 4; ++t) acc[t] = (f32x4){0.f, 0.f, 0.f, 0.f};

    float gmax[9];
    float pA[36], pB[36];

    // ======= phase A: 4 channel-chunks, 2-chunk lookahead pipeline ==========
    CHUNK_LOAD(pA, 0);
    CHUNK_LOAD(pB, 1);
    PHA_PROC(pA, 0, 1);
    CHUNK_LOAD(pA, 2);
    PHA_PROC(pB, 1, 0);
    CHUNK_LOAD(pB, 3);
    PHA_PROC(pA, 2, 0);
    PHA_PROC(pB, 3, 0);

    // ======= gmax chunk =====================================================
    {
        const uint4* wa = (const uint4*)ws;
        uint4 Ahi4 = wa[((g * 5 + 4) * 64 + l) * 2];
        uint4 Alo4 = wa[((g * 5 + 4) * 64 + l) * 2 + 1];
        uint4 v0; v0.x = packbf(gmax[0], gmax[1]); v0.y = packbf(gmax[2], gmax[3]);
                  v0.z = packbf(gmax[4], gmax[5]); v0.w = packbf(gmax[6], gmax[7]);
        uint4 v1; v1.x = packbf(gmax[8], 0.0f); v1.y = 0u; v1.z = 0u; v1.w = 0u;
        uint4 vz; vz.x = 0u; vz.y = 0u; vz.z = 0u; vz.w = 0u;
        slab[g][l * 5 + 0] = v0;
        slab[g][l * 5 + 1] = v1;
        slab[g][l * 5 + 2] = vz;
        slab[g][l * 5 + 3] = vz;
        LDS_FENCE();
        #pragma unroll
        for (int t = 0; t < 4; ++t) {
            uint4 bv = slab[g][(16 * t + ln) * 5 + half];
            acc[t] = __builtin_amdgcn_mfma_f32_16x16x32_bf16(
                __builtin_bit_cast(bf16x8, Ahi4),
                __builtin_bit_cast(bf16x8, bv), acc[t], 0, 0, 0);
            acc[t] = __builtin_amdgcn_mfma_f32_16x16x32_bf16(
                __builtin_bit_cast(bf16x8, Alo4),
                __builtin_bit_cast(bf16x8, bv), acc[t], 0, 0, 0);
        }
        ORDER_FENCE();
    }

    // partial y: D col(ln)=pixel 16t+ln, row(4*half+j)=output o
    #pragma unroll
    for (int t = 0; t < 4; ++t)
        #pragma unroll
        for (int j = 0; j < 4; ++j)
            ldsy[g][16 * t + ln][4 * half + j] = acc[t][j];
    __syncthreads();

    // ======= reduce partials + epilogue (pixel = lane) ======================
    float feat[16];
    #pragma unroll
    for (int o = 0; o < 16; ++o) {
        float t = ldsy[0][l][o] + ldsy[1][l][o] + ldsy[2][l][o] + ldsy[3][l][o];
        feat[o] = mishf(t + b1[o]);
    }

    float feat2[16];
    {
        const float* wc2 = ws + WS_WC2;
        const float* sc  = ws + WS_SC;
        const float* off = ws + WS_OFF;
        #pragma unroll
        for (int o = 0; o < 16; ++o) {
            float a2 = 0.0f;
            #pragma unroll
            for (int i = 0; i < 16; ++i)
                a2 = fmaf(wc2[o * 16 + i], feat[i], a2);
            feat2[o] = feat[o] * mishf(a2 * sc[o] + off[o]);
        }
    }

    float att[9];
    {
        float mx = -1e30f;
        #pragma unroll
        for (int k = 0; k < 9; ++k) {
            float a2 = b3[g * 9 + k];
            const float* r = w3 + (g * 9 + k) * 16;
            #pragma unroll
            for (int i = 0; i < 16; ++i)
                a2 = fmaf(r[i], feat2[i], a2);
            att[k] = a2;
            mx = fmaxf(mx, a2);
        }
        float s = 0.0f;
        #pragma unroll
        for (int k = 0; k < 9; ++k) { att[k] = __expf(att[k] - mx); s += att[k]; }
        float inv = __fdividef(1.0f, s);
        #pragma unroll
        for (int k = 0; k < 9; ++k) att[k] *= inv;
    }

    // ======= aggregation: same chunked 2-deep pipeline ======================
    float* ob = out + (((size_t)b * Cch + g * 16) * Hh + h) * Ww + w;
    CHUNK_LOAD(pA, 0);
    CHUNK_LOAD(pB, 1);
    AGG_PROC(pA, 0);
    CHUNK_LOAD(pA, 2);
    AGG_PROC(pB, 1);
    CHUNK_LOAD(pB, 3);
    AGG_PROC(pA, 2);
    AGG_PROC(pB, 3);
}

extern "C" void kernel_launch(void* const* d_in, const int* in_sizes, int n_in,
                              void* d_out, int out_size, void* d_ws, size_t ws_size,
                              hipStream_t stream) {
    const float* in    = (const float*)d_in[0];
    const float* w1    = (const float*)d_in[1];
    const float* b1    = (const float*)d_in[2];
    const float* w2    = (const float*)d_in[3];
    const float* b2    = (const float*)d_in[4];
    const float* w3    = (const float*)d_in[5];
    const float* b3    = (const float*)d_in[6];
    const float* gamma = (const float*)d_in[7];
    const float* beta  = (const float*)d_in[8];
    const float* mean  = (const float*)d_in[9];
    const float* var   = (const float*)d_in[10];
    float* out = (float*)d_out;
    float* ws  = (float*)d_ws;

    hipLaunchKernelGGL(prep_kernel, dim3(1), dim3(256), 0, stream,
                       w1, w2, b2, gamma, beta, mean, var, ws);

    hipLaunchKernelGGL(revo_kernel, dim3(2048), dim3(256), 0, stream,
                       in, b1, w3, b3, ws, out);
}

// Round 9
// 98.451 us; speedup vs baseline: 2.8726x; 2.8726x over previous
//
#include <hip/hip_runtime.h>
#include <hip/hip_bf16.h>
#include <math.h>

#define Cch 64
#define Hh  256
#define Ww  256
#define HW  (Hh * Ww)

// ws layout (32-bit words):
// [0, 9216): A-frags [18 steps][64 lanes][8 u32] (hi 4, lo 4)
#define WS_WC2  9216     // [16][16] f32 conv2 center taps
#define WS_SC   9472     // [16] BN scale
#define WS_OFF  9488     // [16] BN offset (incl conv2 bias)

typedef __attribute__((ext_vector_type(8))) short bf16x8;
typedef __attribute__((ext_vector_type(4))) float f32x4;

__device__ __forceinline__ float mishf(float x) {
    float e  = __expf(fminf(x, 15.0f));
    float n  = 1.0f + e;
    float n2 = n * n;
    float t  = __fdividef(n2 - 1.0f, n2 + 1.0f);
    return x > 15.0f ? x : x * t;
}

__device__ __forceinline__ unsigned packbf(float a, float b) {
    unsigned short ua = __builtin_bit_cast(unsigned short, __float2bfloat16(a));
    unsigned short ub = __builtin_bit_cast(unsigned short, __float2bfloat16(b));
    return (unsigned)ua | ((unsigned)ub << 16);
}

// A value for (output m, step s, quarter q, j):
// s<16: channel c=16q+s; j<3 -> m_kh(kw=j) col 36+c*3+j; j in 3..5 -> m_kw col
// 228+c*3+(j-3); j>=6 -> 0.  s==16: gc k=j (col q*9+j).  s==17: j==0 -> gc k=8.
__device__ __forceinline__ float conv1_wval2(const float* w1, int m, int s,
                                             int q, int j) {
    if (s < 16) {
        int c = 16 * q + s;
        if (j < 3) return w1[m * 420 + 36 + c * 3 + j];
        if (j < 6) return w1[m * 420 + 228 + c * 3 + (j - 3)];
        return 0.0f;
    } else if (s == 16) {
        return w1[m * 420 + q * 9 + j];
    }
    return (j == 0) ? w1[m * 420 + q * 9 + 8] : 0.0f;
}

__global__ __launch_bounds__(256) void prep_kernel(
    const float* __restrict__ w1, const float* __restrict__ w2,
    const float* __restrict__ b2,
    const float* __restrict__ gamma, const float* __restrict__ beta,
    const float* __restrict__ mean,  const float* __restrict__ var,
    float* __restrict__ ws)
{
    unsigned* wsu = (unsigned*)ws;
    const int tid = threadIdx.x;

    // A-frags: lane holds A[m=lane&15][k=8q+j], q=lane>>4, hi/lo fp32-split
    for (int idx = tid; idx < 1152; idx += 256) {
        int s = idx >> 6, lane = idx & 63;
        int m = lane & 15, q = lane >> 4;
        unsigned hi[4], lo[4];
        #pragma unroll
        for (int jp = 0; jp < 4; ++jp) {
            float hv[2], lv[2];
            #pragma unroll
            for (int e = 0; e < 2; ++e) {
                float v  = conv1_wval2(w1, m, s, q, jp * 2 + e);
                float hf = __bfloat162float(__float2bfloat16(v));
                hv[e] = hf;
                lv[e] = v - hf;
            }
            hi[jp] = packbf(hv[0], hv[1]);
            lo[jp] = packbf(lv[0], lv[1]);
        }
        int b0 = idx * 8;
        #pragma unroll
        for (int i = 0; i < 4; ++i) { wsu[b0 + i] = hi[i]; wsu[b0 + 4 + i] = lo[i]; }
    }

    for (int idx = tid; idx < 256; idx += 256) {
        int o = idx / 16, i = idx % 16;
        ws[WS_WC2 + idx] = w2[o * 144 + i * 9 + 4];
    }
    if (tid < 16) {
        float sc = gamma[tid] * rsqrtf(var[tid] + 1e-5f);
        ws[WS_SC + tid]  = sc;
        ws[WS_OFF + tid] = b2[tid] * sc + beta[tid] - mean[tid] * sc;
    }
}

#define LDS_FENCE() do {                                             \
    asm volatile("s_waitcnt lgkmcnt(0)" ::: "memory");               \
    __builtin_amdgcn_sched_barrier(0);                               \
} while (0)

#define LOAD9(dst, cb) do {                                          \
    const float* r0_ = (cb) + (size_t)hmc * Ww + w;                  \
    const float* r1_ = (cb) + (size_t)h   * Ww + w;                  \
    const float* r2_ = (cb) + (size_t)hpc * Ww + w;                  \
    (dst)[0] = r0_[offm]; (dst)[1] = r0_[0]; (dst)[2] = r0_[offp];   \
    (dst)[3] = r1_[offm]; (dst)[4] = r1_[0]; (dst)[5] = r1_[offp];   \
    (dst)[6] = r2_[offm]; (dst)[7] = r2_[0]; (dst)[8] = r2_[offp];   \
} while (0)

#define MASK9IP(p) do {                                              \
    (p)[0] = (okhm && okm) ? (p)[0] : 0.0f;                          \
    (p)[1] =  okhm         ? (p)[1] : 0.0f;                          \
    (p)[2] = (okhm && okp) ? (p)[2] : 0.0f;                          \
    (p)[3] =  okm          ? (p)[3] : 0.0f;                          \
    (p)[5] =  okp          ? (p)[5] : 0.0f;                          \
    (p)[6] = (okhp && okm) ? (p)[6] : 0.0f;                          \
    (p)[7] =  okhp         ? (p)[7] : 0.0f;                          \
    (p)[8] = (okhp && okp) ? (p)[8] : 0.0f;                          \
} while (0)

__device__ __forceinline__ float dot4(f32x4 a, f32x4 b) {
    float r = a[0] * b[0];
    r = fmaf(a[1], b[1], r);
    r = fmaf(a[2], b[2], r);
    r = fmaf(a[3], b[3], r);
    return r;
}

__global__ __launch_bounds__(256) void revo_kernel(
    const float* __restrict__ in,
    const float* __restrict__ b1,
    const float* __restrict__ w3, const float* __restrict__ b3,
    const float* __restrict__ ws,
    float* __restrict__ out)
{
    const int tid = threadIdx.x;
    const int t   = tid >> 6;          // wave id (0..3): 16-pixel sub-segment
    const int l   = tid & 63;
    const int q   = l >> 4;            // channel-group of this lane
    const int px  = l & 15;            // pixel-in-tile

    const int bid     = blockIdx.x;
    const int logical = ((bid & 7) << 8) + (bid >> 3);  // XCD-chunked
    const int wseg = logical & 3;
    const int h    = (logical >> 2) & (Hh - 1);
    const int b    = logical >> 10;
    const int w    = wseg * 64 + t * 16 + px;

    // tiny wave-private exchange buffers (no barriers anywhere)
    __shared__ f32x4 ldsf[4][16][5];   // [wave][px][q] (+pad)

    const float* base_c = in + ((size_t)b * Cch + 16 * q) * HW;

    const bool okm = (w > 0);
    const bool okp = (w < Ww - 1);
    const int offm = okm ? -1 : 0;
    const int offp = okp ?  1 : 0;

    const int hm = h - 1, hp = h + 1;
    const bool okhm = (hm >= 0), okhp = (hp < Hh);
    const int hmc = okhm ? hm : 0;
    const int hpc = okhp ? hp : Hh - 1;

    const uint4* wa = (const uint4*)ws;

    // ======= conv1: 16 channel-steps + 2 gmax-steps, B built in registers ===
    f32x4 acc = (f32x4){0.f, 0.f, 0.f, 0.f};
    float gmax[9];
    float pT[9], pN[9];

    LOAD9(pT, base_c);                 // channel 16q+0
    #pragma unroll
    for (int s = 0; s < 16; ++s) {
        if (s < 15) LOAD9(pN, base_c + (size_t)(s + 1) * HW);
        MASK9IP(pT);
        if (s == 0) {
            #pragma unroll
            for (int k = 0; k < 9; ++k) gmax[k] = pT[k];
        } else {
            #pragma unroll
            for (int k = 0; k < 9; ++k) gmax[k] = fmaxf(gmax[k], pT[k]);
        }
        float mkh0 = fmaxf(fmaxf(pT[0], pT[3]), pT[6]);
        float mkh1 = fmaxf(fmaxf(pT[1], pT[4]), pT[7]);
        float mkh2 = fmaxf(fmaxf(pT[2], pT[5]), pT[8]);
        float mkw0 = fmaxf(fmaxf(pT[0], pT[1]), pT[2]);
        float mkw1 = fmaxf(fmaxf(pT[3], pT[4]), pT[5]);
        float mkw2 = fmaxf(fmaxf(pT[6], pT[7]), pT[8]);

        uint4 bv;
        bv.x = packbf(mkh0, mkh1);
        bv.y = packbf(mkh2, mkw0);
        bv.z = packbf(mkw1, mkw2);
        bv.w = 0u;

        uint4 Ah = wa[(s * 64 + l) * 2];
        uint4 Al = wa[(s * 64 + l) * 2 + 1];
        acc = __builtin_amdgcn_mfma_f32_16x16x32_bf16(
            __builtin_bit_cast(bf16x8, Ah), __builtin_bit_cast(bf16x8, bv),
            acc, 0, 0, 0);
        acc = __builtin_amdgcn_mfma_f32_16x16x32_bf16(
            __builtin_bit_cast(bf16x8, Al), __builtin_bit_cast(bf16x8, bv),
            acc, 0, 0, 0);

        #pragma unroll
        for (int k = 0; k < 9; ++k) pT[k] = pN[k];
    }
    {   // gmax steps 16,17
        uint4 bv;
        bv.x = packbf(gmax[0], gmax[1]);
        bv.y = packbf(gmax[2], gmax[3]);
        bv.z = packbf(gmax[4], gmax[5]);
        bv.w = packbf(gmax[6], gmax[7]);
        uint4 Ah = wa[(16 * 64 + l) * 2];
        uint4 Al = wa[(16 * 64 + l) * 2 + 1];
        acc = __builtin_amdgcn_mfma_f32_16x16x32_bf16(
            __builtin_bit_cast(bf16x8, Ah), __builtin_bit_cast(bf16x8, bv),
            acc, 0, 0, 0);
        acc = __builtin_amdgcn_mfma_f32_16x16x32_bf16(
            __builtin_bit_cast(bf16x8, Al), __builtin_bit_cast(bf16x8, bv),
            acc, 0, 0, 0);
        uint4 bv2;
        bv2.x = packbf(gmax[8], 0.0f);
        bv2.y = 0u; bv2.z = 0u; bv2.w = 0u;
        uint4 Ah2 = wa[(17 * 64 + l) * 2];
        uint4 Al2 = wa[(17 * 64 + l) * 2 + 1];
        acc = __builtin_amdgcn_mfma_f32_16x16x32_bf16(
            __builtin_bit_cast(bf16x8, Ah2), __builtin_bit_cast(bf16x8, bv2),
            acc, 0, 0, 0);
        acc = __builtin_amdgcn_mfma_f32_16x16x32_bf16(
            __builtin_bit_cast(bf16x8, Al2), __builtin_bit_cast(bf16x8, bv2),
            acc, 0, 0, 0);
    }

    // acc[j] = y[o=4q+j][px] complete. ======= epilogue, split across q ======
    f32x4 b1q = ((const f32x4*)b1)[q];
    f32x4 fp;
    #pragma unroll
    for (int j = 0; j < 4; ++j) fp[j] = mishf(acc[j] + b1q[j]);

    ldsf[t][px][q] = fp;
    LDS_FENCE();
    f32x4 F0 = ldsf[t][px][0], F1 = ldsf[t][px][1],
          F2 = ldsf[t][px][2], F3 = ldsf[t][px][3];
    LDS_FENCE();

    // conv2 rows o=4q..4q+3 + folded BN + mish gate
    const f32x4* wc2v = (const f32x4*)(ws + WS_WC2);
    f32x4 scq  = ((const f32x4*)(ws + WS_SC))[q];
    f32x4 offq = ((const f32x4*)(ws + WS_OFF))[q];
    f32x4 f2p;
    #pragma unroll
    for (int j = 0; j < 4; ++j) {
        int o = 4 * q + j;
        float a2 = dot4(wc2v[o * 4 + 0], F0) + dot4(wc2v[o * 4 + 1], F1)
                 + dot4(wc2v[o * 4 + 2], F2) + dot4(wc2v[o * 4 + 3], F3);
        f2p[j] = fp[j] * mishf(a2 * scq[j] + offq[j]);
    }

    ldsf[t][px][q] = f2p;
    LDS_FENCE();
    f32x4 G0 = ldsf[t][px][0], G1 = ldsf[t][px][1],
          G2 = ldsf[t][px][2], G3 = ldsf[t][px][3];
    LDS_FENCE();

    // conv3: this group's 9 logits + softmax
    const f32x4* w3v = (const f32x4*)w3;
    float att[9];
    {
        float mx = -1e30f;
        #pragma unroll
        for (int k = 0; k < 9; ++k) {
            int row = q * 9 + k;
            float a2 = b3[row];
            a2 += dot4(w3v[row * 4 + 0], G0) + dot4(w3v[row * 4 + 1], G1)
                + dot4(w3v[row * 4 + 2], G2) + dot4(w3v[row * 4 + 3], G3);
            att[k] = a2;
            mx = fmaxf(mx, a2);
        }
        float sum = 0.0f;
        #pragma unroll
        for (int k = 0; k < 9; ++k) { att[k] = __expf(att[k] - mx); sum += att[k]; }
        float inv = __fdividef(1.0f, sum);
        #pragma unroll
        for (int k = 0; k < 9; ++k) att[k] *= inv;
    }

    // ======= aggregation: this group's 16 channels, 1-ahead pipeline ========
    float* ob = out + (((size_t)b * Cch + 16 * q) * Hh + h) * Ww + w;
    LOAD9(pT, base_c);
    #pragma unroll
    for (int cc = 0; cc < 16; ++cc) {
        if (cc < 15) LOAD9(pN, base_c + (size_t)(cc + 1) * HW);
        float a2 = 0.0f;
        a2 = fmaf((okhm && okm) ? pT[0] : 0.0f, att[0], a2);
        a2 = fmaf( okhm         ? pT[1] : 0.0f, att[1], a2);
        a2 = fmaf((okhm && okp) ? pT[2] : 0.0f, att[2], a2);
        a2 = fmaf( okm          ? pT[3] : 0.0f, att[3], a2);
        a2 = fmaf( pT[4],                       att[4], a2);
        a2 = fmaf( okp          ? pT[5] : 0.0f, att[5], a2);
        a2 = fmaf((okhp && okm) ? pT[6] : 0.0f, att[6], a2);
        a2 = fmaf( okhp         ? pT[7] : 0.0f, att[7], a2);
        a2 = fmaf((okhp && okp) ? pT[8] : 0.0f, att[8], a2);
        ob[(size_t)cc * HW] = a2;
        #pragma unroll
        for (int k = 0; k < 9; ++k) pT[k] = pN[k];
    }
}

extern "C" void kernel_launch(void* const* d_in, const int* in_sizes, int n_in,
                              void* d_out, int out_size, void* d_ws, size_t ws_size,
                              hipStream_t stream) {
    const float* in    = (const float*)d_in[0];
    const float* w1    = (const float*)d_in[1];
    const float* b1    = (const float*)d_in[2];
    const float* w2    = (const float*)d_in[3];
    const float* b2    = (const float*)d_in[4];
    const float* w3    = (const float*)d_in[5];
    const float* b3    = (const float*)d_in[6];
    const float* gamma = (const float*)d_in[7];
    const float* beta  = (const float*)d_in[8];
    const float* mean  = (const float*)d_in[9];
    const float* var   = (const float*)d_in[10];
    float* out = (float*)d_out;
    float* ws  = (float*)d_ws;

    hipLaunchKernelGGL(prep_kernel, dim3(1), dim3(256), 0, stream,
                       w1, w2, b2, gamma, beta, mean, var, ws);

    hipLaunchKernelGGL(revo_kernel, dim3(2048), dim3(256), 0, stream,
                       in, b1, w3, b3, ws, out);
}